// Round 3
// baseline (46.573 us; speedup 1.0000x reference)
//
#include <hip/hip_runtime.h>
#include <hip/hip_bf16.h>

// StreamingConv == GEMM: C[b,o] = sum_k A[b,k] * W[o,k]
//   A = curr_input [256][16384] f32 (K-contiguous), W = weight [1024][16384] f32
// R3: latency-bound diagnosis (all pipes <15%). Fix: 128x128 tile (8 waves),
// 2-deep register prefetch (P/Q sets, static indexing) + double-buffered LDS,
// SPLITK=32 -> 512 blocks = 2/CU. Partials to d_ws, then reduce.

#define B_DIM 256
#define CO    1024
#define KTOT  16384
#define BM    128
#define BN    128
#define BK    64
#define SA    (BK + 8)            // bf16 LDS row stride: 144B
#define OUT_ELEMS (B_DIM * CO)    // 262144

typedef __attribute__((ext_vector_type(8))) short  short8;
typedef __attribute__((ext_vector_type(4))) float  f32x4;
typedef __attribute__((ext_vector_type(4))) unsigned short u16x4;

__device__ __forceinline__ unsigned short f2bf(float f) {
    union { __bf16 h; unsigned short u; } cv;
    cv.h = (__bf16)f;
    return cv.u;
}

template <int SPLITK, bool USE_WS>
__global__ __launch_bounds__(512, 4)
void sconv_gemm(const float* __restrict__ A, const float* __restrict__ W,
                float* __restrict__ out, float* __restrict__ ws) {
    constexpr int KC = KTOT / SPLITK;
    constexpr int KITERS = KC / BK;
    static_assert(KITERS % 2 == 0, "pipeline assumes even KITERS");

    __shared__ unsigned short lA[2][BM * SA];
    __shared__ unsigned short lB[2][BN * SA];

    const int tid = threadIdx.x;
    const int bm = (blockIdx.x >> 3) * BM;   // 2 M-tiles
    const int bn = (blockIdx.x & 7) * BN;    // 8 N-tiles
    const int k0 = blockIdx.y * KC;

    const float* Abase = A + (size_t)bm * KTOT + k0;
    const float* Wbase = W + (size_t)bn * KTOT + k0;

    // staging: 128 rows x 16 float4 per matrix tile = 2048 float4; 4/thread
    int srow[4], sq[4];
    #pragma unroll
    for (int i = 0; i < 4; ++i) {
        int idx = i * 512 + tid;
        srow[i] = idx >> 4;
        sq[i]   = (idx & 15) * 4;
    }

    float4 pa[4], pw[4];   // register set P (even tiles)
    float4 qa[4], qw[4];   // register set Q (odd tiles)

#define LOAD(ra, rw, T)                                                        \
    {                                                                          \
        const float* Ab = Abase + (T) * BK;                                    \
        const float* Wb = Wbase + (T) * BK;                                    \
        _Pragma("unroll")                                                      \
        for (int i = 0; i < 4; ++i) {                                          \
            ra[i] = *(const float4*)(Ab + (size_t)srow[i] * KTOT + sq[i]);     \
            rw[i] = *(const float4*)(Wb + (size_t)srow[i] * KTOT + sq[i]);     \
        }                                                                      \
    }

#define STORE(ra, rw, BUF)                                                     \
    {                                                                          \
        _Pragma("unroll")                                                      \
        for (int i = 0; i < 4; ++i) {                                          \
            u16x4 xa, xw;                                                      \
            xa.x = f2bf(ra[i].x); xa.y = f2bf(ra[i].y);                        \
            xa.z = f2bf(ra[i].z); xa.w = f2bf(ra[i].w);                        \
            xw.x = f2bf(rw[i].x); xw.y = f2bf(rw[i].y);                        \
            xw.z = f2bf(rw[i].z); xw.w = f2bf(rw[i].w);                        \
            *(u16x4*)(&lA[BUF][srow[i] * SA + sq[i]]) = xa;                    \
            *(u16x4*)(&lB[BUF][srow[i] * SA + sq[i]]) = xw;                    \
        }                                                                      \
    }

    // wave -> 64x32 sub-tile of the 128x128 block tile (2x4 wave grid)
    const int wid  = tid >> 6;
    const int lane = tid & 63;
    const int wm = (wid >> 2) * 64;          // 0 / 64
    const int wn = (wid & 3) * 32;           // 0 / 32 / 64 / 96
    const int frow = lane & 15;
    const int fk   = (lane >> 4) * 8;

    f32x4 acc[4][2] = {};

#define MFMA_TILE(BUF)                                                         \
    {                                                                          \
        _Pragma("unroll")                                                      \
        for (int kk = 0; kk < 2; ++kk) {                                       \
            short8 af[4], bfr[2];                                              \
            _Pragma("unroll")                                                  \
            for (int mi = 0; mi < 4; ++mi)                                     \
                af[mi] = *(const short8*)(                                     \
                    &lA[BUF][(wm + mi * 16 + frow) * SA + kk * 32 + fk]);      \
            _Pragma("unroll")                                                  \
            for (int ni = 0; ni < 2; ++ni)                                     \
                bfr[ni] = *(const short8*)(                                    \
                    &lB[BUF][(wn + ni * 16 + frow) * SA + kk * 32 + fk]);      \
            _Pragma("unroll")                                                  \
            for (int mi = 0; mi < 4; ++mi)                                     \
                _Pragma("unroll")                                              \
                for (int ni = 0; ni < 2; ++ni)                                 \
                    acc[mi][ni] = __builtin_amdgcn_mfma_f32_16x16x32_bf16(     \
                        af[mi], bfr[ni], acc[mi][ni], 0, 0, 0);                \
        }                                                                      \
    }

    // prologue: tile0 -> LDS buf0 (immediate), tile1 -> Q regs (in flight)
    LOAD(pa, pw, 0);
    STORE(pa, pw, 0);
    LOAD(qa, qw, 1);

    #pragma unroll
    for (int t = 0; t < KITERS; t += 2) {
        // --- even tile t: compute buf0 ---
        __syncthreads();                       // buf0 stores visible
        if (t + 2 < KITERS) LOAD(pa, pw, t + 2);   // issue early, flies over MFMA
        MFMA_TILE(0);
        if (t + 1 < KITERS) STORE(qa, qw, 1);  // waits Q (issued a full iter ago)

        // --- odd tile t+1: compute buf1 ---
        __syncthreads();
        if (t + 3 < KITERS) LOAD(qa, qw, t + 3);
        if (t + 1 < KITERS) MFMA_TILE(1);
        if (t + 2 < KITERS) STORE(pa, pw, 0);
    }

#undef LOAD
#undef STORE
#undef MFMA_TILE

    // epilogue: C/D layout 16x16x32: col = lane&15, row = (lane>>4)*4 + j
    const int crow = (lane >> 4) * 4;
    const int ccol = lane & 15;
    float* pout = USE_WS ? (ws + (size_t)blockIdx.y * OUT_ELEMS) : out;
    #pragma unroll
    for (int mi = 0; mi < 4; ++mi) {
        const int gr = bm + wm + mi * 16 + crow;
        #pragma unroll
        for (int ni = 0; ni < 2; ++ni) {
            const int gc = bn + wn + ni * 16 + ccol;
            #pragma unroll
            for (int j = 0; j < 4; ++j) {
                if (USE_WS) {
                    pout[(size_t)(gr + j) * CO + gc] = acc[mi][ni][j];
                } else {
                    unsafeAtomicAdd(pout + (size_t)(gr + j) * CO + gc, acc[mi][ni][j]);
                }
            }
        }
    }
}

template <int SPLITK>
__global__ __launch_bounds__(256)
void reduce_splitk(const float* __restrict__ ws, float* __restrict__ out) {
    const int i = blockIdx.x * 256 + threadIdx.x;   // float4 index
    const float4* p = (const float4*)ws + i;
    float4 s = p[0];
    #pragma unroll
    for (int sdx = 1; sdx < SPLITK; ++sdx) {
        float4 v = p[(size_t)sdx * (OUT_ELEMS / 4)];
        s.x += v.x; s.y += v.y; s.z += v.z; s.w += v.w;
    }
    ((float4*)out)[i] = s;
}

extern "C" void kernel_launch(void* const* d_in, const int* in_sizes, int n_in,
                              void* d_out, int out_size, void* d_ws, size_t ws_size,
                              hipStream_t stream) {
    const float* A = (const float*)d_in[0];
    const float* W = (const float*)d_in[1];
    float* out = (float*)d_out;
    float* ws  = (float*)d_ws;

    const size_t need32 = (size_t)32 * OUT_ELEMS * sizeof(float);  // 33.6 MB
    const size_t need16 = (size_t)16 * OUT_ELEMS * sizeof(float);  // 16.8 MB

    if (ws_size >= need32) {
        dim3 grid(16, 32);                       // 512 blocks = 2/CU
        sconv_gemm<32, true><<<grid, 512, 0, stream>>>(A, W, out, ws);
        reduce_splitk<32><<<OUT_ELEMS / 4 / 256, 256, 0, stream>>>(ws, out);
    } else if (ws_size >= need16) {
        dim3 grid(16, 16);                       // 256 blocks
        sconv_gemm<16, true><<<grid, 512, 0, stream>>>(A, W, out, ws);
        reduce_splitk<16><<<OUT_ELEMS / 4 / 256, 256, 0, stream>>>(ws, out);
    } else {
        hipMemsetAsync(d_out, 0, (size_t)out_size * sizeof(float), stream);
        dim3 grid(16, 32);
        sconv_gemm<32, false><<<grid, 512, 0, stream>>>(A, W, out, ws);
    }
}

// Round 4
// 39.965 us; speedup vs baseline: 1.1653x; 1.1653x over previous
//
#include <hip/hip_runtime.h>
#include <hip/hip_bf16.h>

// StreamingConv == GEMM: C[b,o] = sum_k A[b,k]*W[o,k];  A[256][16384], W[1024][16384] f32.
// R4: R3's VGPR_Count=64 proved the compiler flattened the register-prefetch pipeline.
// Fix: global_load_lds (no staging VGPRs) + raw s_barrier + counted vmcnt(8) so loads
// stay in flight across barriers. f32 staged in LDS (XOR-swizzled via pre-swizzled
// global source), f32->bf16 on read, 16x16x32 MFMA. BM=256 (W read once), BN=256,
// SPLITK=64 -> 256 blocks = 1/CU. bf16 partials to d_ws + reduce kernel.

#define CO    1024
#define KTOT  16384
#define BM    256
#define BN    256
#define BK    32                 // f32 k-step; row = 128 B
#define SPLITK 64
#define KC    (KTOT / SPLITK)    // 256
#define KITERS (KC / BK)         // 8
#define OUT_ELEMS (BM * CO)      // 262144

typedef __attribute__((ext_vector_type(8))) short short8;
typedef __attribute__((ext_vector_type(4))) float f32x4;

__device__ __forceinline__ unsigned short f2bf(float f) {
    union { __bf16 h; unsigned short u; } c; c.h = (__bf16)f; return c.u;
}

__device__ __forceinline__ void gl_lds16(const float* g, const float* lds_uniform) {
    __builtin_amdgcn_global_load_lds(
        (const __attribute__((address_space(1))) void*)g,
        (__attribute__((address_space(3))) void*)lds_uniform, 16, 0, 0);
}

template <bool USE_WS>
__global__ __launch_bounds__(512, 2)
void sconv_gemm(const float* __restrict__ A, const float* __restrict__ W,
                float* __restrict__ out, unsigned short* __restrict__ wsb) {
    // LDS tiles hold f32, XOR-swizzled: lX[r][g] (g = 16B group 0..7) holds
    // global k-group (g ^ (r&7)) of row r.  64 KB per buffer, 128 KB total.
    __shared__ float lA[2][BM * BK];
    __shared__ float lB[2][BN * BK];

    const int tid  = threadIdx.x;
    const int wid  = tid >> 6;
    const int lane = tid & 63;
    const int bn = blockIdx.x * BN;     // 4 n-tiles
    const int k0 = blockIdx.y * KC;     // 64 k-chunks

    // ---- staging decomposition: 2048 16B-slots per matrix tile, 4 per thread ----
    // slot s -> row r = s>>3, lds 16B-group g = s&7; source k-group = g ^ (r&7)
    // (swizzle permutes 16B chunks WITHIN one 128B row -> global coalescing intact)
    int arow[4], agk[4], ldsoff[4];
    #pragma unroll
    for (int j = 0; j < 4; ++j) {
        int s = j * 512 + tid;
        arow[j]  = s >> 3;
        agk[j]   = (s & 7) ^ (arow[j] & 7);
        ldsoff[j] = (j * 512 + wid * 64) * 4;   // wave-uniform base slot * 4 floats
    }

    const float* Asrc = A + k0;
    const float* Wsrc = W + (size_t)bn * KTOT + k0;

#define STAGE(BUF, T) {                                                           \
        _Pragma("unroll")                                                         \
        for (int j = 0; j < 4; ++j)                                               \
            gl_lds16(Asrc + (size_t)arow[j] * KTOT + (T) * BK + agk[j] * 4,       \
                     &lA[BUF][ldsoff[j]]);                                        \
        _Pragma("unroll")                                                         \
        for (int j = 0; j < 4; ++j)                                               \
            gl_lds16(Wsrc + (size_t)arow[j] * KTOT + (T) * BK + agk[j] * 4,       \
                     &lB[BUF][ldsoff[j]]);                                        \
    }

    // ---- wave -> 128x64 output sub-tile (2x4 wave grid over 256x256) ----
    const int wm   = (wid >> 2) * 128;
    const int wn   = (wid & 3) * 64;
    const int frow = lane & 15;
    const int fkg  = (lane >> 4) * 2;    // 16B-group of this lane's k-start (k=8*(lane>>4))

    f32x4 acc[8][4] = {};

#define COMPUTE(BUF) {                                                            \
        short8 bfr[4];                                                            \
        _Pragma("unroll")                                                         \
        for (int ni = 0; ni < 4; ++ni) {                                          \
            int r = wn + ni * 16 + frow;                                          \
            int sw = r & 7;                                                       \
            f32x4 v0 = *(const f32x4*)&lB[BUF][r * BK + ((fkg ^ sw) * 4)];        \
            f32x4 v1 = *(const f32x4*)&lB[BUF][r * BK + (((fkg + 1) ^ sw) * 4)];  \
            short8 tb;                                                            \
            tb[0]=f2bf(v0[0]); tb[1]=f2bf(v0[1]); tb[2]=f2bf(v0[2]); tb[3]=f2bf(v0[3]); \
            tb[4]=f2bf(v1[0]); tb[5]=f2bf(v1[1]); tb[6]=f2bf(v1[2]); tb[7]=f2bf(v1[3]); \
            bfr[ni] = tb;                                                         \
        }                                                                         \
        _Pragma("unroll")                                                         \
        for (int mi = 0; mi < 8; ++mi) {                                          \
            int r = wm + mi * 16 + frow;                                          \
            int sw = r & 7;                                                       \
            f32x4 v0 = *(const f32x4*)&lA[BUF][r * BK + ((fkg ^ sw) * 4)];        \
            f32x4 v1 = *(const f32x4*)&lA[BUF][r * BK + (((fkg + 1) ^ sw) * 4)];  \
            short8 af;                                                            \
            af[0]=f2bf(v0[0]); af[1]=f2bf(v0[1]); af[2]=f2bf(v0[2]); af[3]=f2bf(v0[3]); \
            af[4]=f2bf(v1[0]); af[5]=f2bf(v1[1]); af[6]=f2bf(v1[2]); af[7]=f2bf(v1[3]); \
            _Pragma("unroll")                                                     \
            for (int ni = 0; ni < 4; ++ni)                                        \
                acc[mi][ni] = __builtin_amdgcn_mfma_f32_16x16x32_bf16(            \
                    af, bfr[ni], acc[mi][ni], 0, 0, 0);                           \
        }                                                                         \
    }

    STAGE(0, 0);
    #pragma unroll
    for (int t = 0; t < KITERS; ++t) {
        const int buf = t & 1;
        // barrier 1: everyone finished reading buf^1 (computed last iter) before overwrite
        asm volatile("" ::: "memory");
        __builtin_amdgcn_s_barrier();
        asm volatile("" ::: "memory");
        if (t + 1 < KITERS) {
            STAGE(buf ^ 1, t + 1);
            asm volatile("s_waitcnt vmcnt(8)" ::: "memory");  // buf's 8 loads (prev iter) done
        } else {
            asm volatile("s_waitcnt vmcnt(0)" ::: "memory");
        }
        // barrier 2: all waves' buf loads complete -> safe to read
        __builtin_amdgcn_s_barrier();
        asm volatile("" ::: "memory");
        COMPUTE(buf);
    }
#undef STAGE
#undef COMPUTE

    // epilogue: C/D 16x16x32: col = lane&15, row = (lane>>4)*4 + j
    const int crow = (lane >> 4) * 4;
    const int ccol = lane & 15;
    if (USE_WS) {
        unsigned short* slice = wsb + (size_t)blockIdx.y * OUT_ELEMS;
        #pragma unroll
        for (int mi = 0; mi < 8; ++mi) {
            #pragma unroll
            for (int ni = 0; ni < 4; ++ni) {
                const int col = bn + wn + ni * 16 + ccol;
                #pragma unroll
                for (int j = 0; j < 4; ++j) {
                    const int row = wm + mi * 16 + crow + j;
                    slice[(size_t)row * CO + col] = f2bf(acc[mi][ni][j]);
                }
            }
        }
    } else {
        #pragma unroll
        for (int mi = 0; mi < 8; ++mi) {
            #pragma unroll
            for (int ni = 0; ni < 4; ++ni) {
                const int col = bn + wn + ni * 16 + ccol;
                #pragma unroll
                for (int j = 0; j < 4; ++j) {
                    const int row = wm + mi * 16 + crow + j;
                    unsafeAtomicAdd(out + (size_t)row * CO + col, acc[mi][ni][j]);
                }
            }
        }
    }
}

// out[i] = sum over 64 bf16 partial slices
__global__ __launch_bounds__(256)
void reduce_splitk_bf16(const unsigned short* __restrict__ ws, float* __restrict__ out) {
    const int i = blockIdx.x * 256 + threadIdx.x;     // 8-element group index
    const short8* base = (const short8*)ws;
    float s[8] = {0, 0, 0, 0, 0, 0, 0, 0};
    #pragma unroll
    for (int sdx = 0; sdx < SPLITK; ++sdx) {
        short8 v = base[(size_t)sdx * (OUT_ELEMS / 8) + i];
        #pragma unroll
        for (int e = 0; e < 8; ++e) {
            unsigned int u = ((unsigned int)(unsigned short)v[e]) << 16;
            s[e] += __builtin_bit_cast(float, u);
        }
    }
    float4 o0 = make_float4(s[0], s[1], s[2], s[3]);
    float4 o1 = make_float4(s[4], s[5], s[6], s[7]);
    ((float4*)out)[(size_t)i * 2]     = o0;
    ((float4*)out)[(size_t)i * 2 + 1] = o1;
}

extern "C" void kernel_launch(void* const* d_in, const int* in_sizes, int n_in,
                              void* d_out, int out_size, void* d_ws, size_t ws_size,
                              hipStream_t stream) {
    const float* A = (const float*)d_in[0];
    const float* W = (const float*)d_in[1];
    float* out = (float*)d_out;
    unsigned short* ws = (unsigned short*)d_ws;

    const size_t ws_needed = (size_t)SPLITK * OUT_ELEMS * sizeof(unsigned short); // 32 MB
    dim3 grid(CO / BN, SPLITK);   // 4 x 64 = 256 blocks = 1/CU

    if (ws_size >= ws_needed) {
        sconv_gemm<true><<<grid, 512, 0, stream>>>(A, W, out, ws);
        reduce_splitk_bf16<<<OUT_ELEMS / 8 / 256, 256, 0, stream>>>(ws, out);
    } else {
        hipMemsetAsync(d_out, 0, (size_t)out_size * sizeof(float), stream);
        sconv_gemm<false><<<grid, 512, 0, stream>>>(A, W, out, ws);
    }
}